// Round 1
// baseline (7407.536 us; speedup 1.0000x reference)
//
#include <hip/hip_runtime.h>
#include <stdint.h>

#define B_   128
#define T_   256
#define IN_  512
#define H_   1024
#define NG_  4096   // 4*H (gate-interleaved rows)
#define KC_  1536   // IN+H
#define OUT_ 512

typedef __bf16 bf16x8 __attribute__((ext_vector_type(8)));
typedef float  f32x4  __attribute__((ext_vector_type(4)));

__device__ __forceinline__ ushort f2bf(float f) {
    union { float f; uint32_t u; } v; v.f = f;
    uint32_t u = v.u;
    return (ushort)((u + 0x7FFFu + ((u >> 16) & 1u)) >> 16);  // RNE
}

__device__ __forceinline__ f32x4 mfma16(bf16x8 a, bf16x8 b, f32x4 c) {
    return __builtin_amdgcn_mfma_f32_16x16x32_bf16(a, b, c, 0, 0, 0);
}

// ---------------- prep kernels ----------------

__global__ void prep_w(const float* __restrict__ Wf, const float* __restrict__ Wi,
                       const float* __restrict__ Wc, const float* __restrict__ Wo,
                       ushort* __restrict__ Wcat) {
    int row = blockIdx.x;            // 0..4095 (= 4*j+g)
    int j = row >> 2, g = row & 3;
    const float* W = (g == 0) ? Wf : (g == 1) ? Wi : (g == 2) ? Wc : Wo;
    for (int k = threadIdx.x; k < KC_; k += 256)
        Wcat[(size_t)row * KC_ + k] = f2bf(W[(size_t)j * KC_ + k]);
}

__global__ void prep_bias(const float* __restrict__ bf_, const float* __restrict__ bi_,
                          const float* __restrict__ bc_, const float* __restrict__ bo_,
                          float* __restrict__ bias) {
    int idx = blockIdx.x * 256 + threadIdx.x;  // 16 blocks -> 4096
    int j = idx >> 2, g = idx & 3;
    const float* b = (g == 0) ? bf_ : (g == 1) ? bi_ : (g == 2) ? bc_ : bo_;
    bias[idx] = b[j];
}

__global__ void prep_wout(const float* __restrict__ W, ushort* __restrict__ Wb) {
    int row = blockIdx.x;  // 512
    for (int k = threadIdx.x; k < H_; k += 256)
        Wb[(size_t)row * H_ + k] = f2bf(W[(size_t)row * H_ + k]);
}

__global__ void prep_x(const float* __restrict__ x, ushort* __restrict__ xT) {
    int bid = blockIdx.x;            // t*128 + b
    int t = bid >> 7, b = bid & 127;
    const float* src = x  + ((size_t)b * T_ + t) * IN_;
    ushort*      dst = xT + ((size_t)t * B_ + b) * IN_;
    for (int k = threadIdx.x; k < IN_; k += 256) dst[k] = f2bf(src[k]);
}

__global__ void prep_zero(ushort* __restrict__ hs0, float* __restrict__ c) {
    int idx = blockIdx.x * 256 + threadIdx.x;  // 512*256 = 131072 = B_*H_
    hs0[idx] = 0;
    c[idx]   = 0.f;
}

// ---------------- per-timestep fused GEMM + gate kernel ----------------
// grid 64 blocks: block bx owns gate-columns [64*bx, 64*bx+64) of the
// gate-interleaved [128, 4096] pre-activation matrix = 16 complete hidden units.

__launch_bounds__(256, 2)
__global__ void lstm_step(const ushort* __restrict__ xT,
                          const ushort* __restrict__ Wcat,
                          const float* __restrict__ bias,
                          ushort* hs, float* c_state, int t)
{
    __shared__ float smem_f[128 * 65];           // 33.3 KB, aliased A/B staging + gate scratch
    ushort* As = (ushort*)smem_f;                // [128][64] bf16, XOR-swizzled
    ushort* Bs = As + 128 * 64;                  // [64][64]  bf16, XOR-swizzled

    const int tid  = threadIdx.x;
    const int lane = tid & 63;
    const int wave = tid >> 6;
    const int wm = (wave >> 1) * 64;
    const int wn = (wave & 1) * 32;
    const int nbase = blockIdx.x * 64;

    const ushort* hprev = hs + (size_t)t * (B_ * H_);

    f32x4 acc[4][2];
#pragma unroll
    for (int i = 0; i < 4; i++)
#pragma unroll
        for (int j = 0; j < 2; j++) acc[i][j] = (f32x4){0.f, 0.f, 0.f, 0.f};

    for (int kc = 0; kc < KC_ / 64; ++kc) {
        const int k0 = kc * 64;
        __syncthreads();
        // stage A [128][64]: cols k0..k0+63 of combined [x_t | h_prev]
#pragma unroll
        for (int it = 0; it < 4; ++it) {
            int g = it * 256 + tid;     // 0..1023
            int row = g >> 3;
            int seg = g & 7;
            const ushort* src;
            if (k0 < IN_) src = xT + ((size_t)t * B_ + row) * IN_ + k0 + seg * 8;
            else          src = hprev + (size_t)row * H_ + (k0 - IN_) + seg * 8;
            uint4 v = *(const uint4*)src;
            int dstg = seg ^ (row & 7);
            *(uint4*)&As[row * 64 + dstg * 8] = v;
        }
        // stage B [64][64]: Wcat rows nbase..nbase+63
#pragma unroll
        for (int it = 0; it < 2; ++it) {
            int g = it * 256 + tid;     // 0..511
            int row = g >> 3;
            int seg = g & 7;
            const ushort* src = Wcat + (size_t)(nbase + row) * KC_ + k0 + seg * 8;
            uint4 v = *(const uint4*)src;
            int dstg = seg ^ (row & 7);
            *(uint4*)&Bs[row * 64 + dstg * 8] = v;
        }
        __syncthreads();
        // 2 MFMA k-steps of 32
#pragma unroll
        for (int ks = 0; ks < 2; ++ks) {
            const int kg = ks * 4 + (lane >> 4);    // 8-elem group index in row
            bf16x8 af[4], bfr[2];
#pragma unroll
            for (int mi = 0; mi < 4; ++mi) {
                int row = wm + mi * 16 + (lane & 15);
                int gi = kg ^ (row & 7);
                af[mi] = *(const bf16x8*)&As[row * 64 + gi * 8];
            }
#pragma unroll
            for (int ni = 0; ni < 2; ++ni) {
                int row = wn + ni * 16 + (lane & 15);
                int gi = kg ^ (row & 7);
                bfr[ni] = *(const bf16x8*)&Bs[row * 64 + gi * 8];
            }
#pragma unroll
            for (int mi = 0; mi < 4; ++mi)
#pragma unroll
                for (int ni = 0; ni < 2; ++ni)
                    acc[mi][ni] = mfma16(af[mi], bfr[ni], acc[mi][ni]);
        }
    }

    // epilogue: bias + activation -> gate scratch LDS [128][65]
    __syncthreads();
    float* gbuf = smem_f;
#pragma unroll
    for (int mi = 0; mi < 4; ++mi) {
#pragma unroll
        for (int ni = 0; ni < 2; ++ni) {
            int col = wn + ni * 16 + (lane & 15);
            float bv = bias[nbase + col];
#pragma unroll
            for (int q = 0; q < 4; ++q) {
                int row = wm + mi * 16 + (lane >> 4) * 4 + q;
                float v = acc[mi][ni][q] + bv;
                if ((col & 3) == 2) v = tanhf(v);           // c~ gate
                else                v = 1.f / (1.f + __expf(-v));  // f,i,o
                gbuf[row * 65 + col] = v;
            }
        }
    }
    __syncthreads();

    // elementwise cell/hidden update: 128 rows x 16 units
    ushort* hout = hs + (size_t)(t + 1) * (B_ * H_);
#pragma unroll
    for (int it = 0; it < 8; ++it) {
        int item = it * 256 + tid;      // 0..2047
        int u = item & 15;
        int r = item >> 4;
        float f  = gbuf[r * 65 + 4 * u + 0];
        float i  = gbuf[r * 65 + 4 * u + 1];
        float ct = gbuf[r * 65 + 4 * u + 2];
        float o  = gbuf[r * 65 + 4 * u + 3];
        int ug = (nbase >> 2) + u;
        size_t ci = (size_t)r * H_ + ug;
        float cn = f * c_state[ci] + i * ct;
        c_state[ci] = cn;
        hout[ci] = f2bf(o * tanhf(cn));
    }
}

// ---------------- output projection GEMM ----------------
// hsflat [32768][1024] bf16 (row rt = t*128+b), Wout [512][1024] bf16,
// out[b][t][o] fp32. Grid 2048: 256 m-tiles x 8 n-tiles.

__launch_bounds__(256, 2)
__global__ void out_gemm(const ushort* __restrict__ hsflat,
                         const ushort* __restrict__ Wout,
                         const float* __restrict__ bout,
                         float* __restrict__ out)
{
    __shared__ ushort As[128 * 64];
    __shared__ ushort Bs[64 * 64];
    const int tid  = threadIdx.x;
    const int lane = tid & 63;
    const int wave = tid >> 6;
    const int wm = (wave >> 1) * 64;
    const int wn = (wave & 1) * 32;
    const int mbase = (blockIdx.x >> 3) * 128;
    const int nbase = (blockIdx.x & 7) * 64;

    f32x4 acc[4][2];
#pragma unroll
    for (int i = 0; i < 4; i++)
#pragma unroll
        for (int j = 0; j < 2; j++) acc[i][j] = (f32x4){0.f, 0.f, 0.f, 0.f};

    for (int kc = 0; kc < H_ / 64; ++kc) {
        const int k0 = kc * 64;
        __syncthreads();
#pragma unroll
        for (int it = 0; it < 4; ++it) {
            int g = it * 256 + tid;
            int row = g >> 3;
            int seg = g & 7;
            uint4 v = *(const uint4*)(hsflat + (size_t)(mbase + row) * H_ + k0 + seg * 8);
            int dstg = seg ^ (row & 7);
            *(uint4*)&As[row * 64 + dstg * 8] = v;
        }
#pragma unroll
        for (int it = 0; it < 2; ++it) {
            int g = it * 256 + tid;
            int row = g >> 3;
            int seg = g & 7;
            uint4 v = *(const uint4*)(Wout + (size_t)(nbase + row) * H_ + k0 + seg * 8);
            int dstg = seg ^ (row & 7);
            *(uint4*)&Bs[row * 64 + dstg * 8] = v;
        }
        __syncthreads();
#pragma unroll
        for (int ks = 0; ks < 2; ++ks) {
            const int kg = ks * 4 + (lane >> 4);
            bf16x8 af[4], bfr[2];
#pragma unroll
            for (int mi = 0; mi < 4; ++mi) {
                int row = wm + mi * 16 + (lane & 15);
                int gi = kg ^ (row & 7);
                af[mi] = *(const bf16x8*)&As[row * 64 + gi * 8];
            }
#pragma unroll
            for (int ni = 0; ni < 2; ++ni) {
                int row = wn + ni * 16 + (lane & 15);
                int gi = kg ^ (row & 7);
                bfr[ni] = *(const bf16x8*)&Bs[row * 64 + gi * 8];
            }
#pragma unroll
            for (int mi = 0; mi < 4; ++mi)
#pragma unroll
                for (int ni = 0; ni < 2; ++ni)
                    acc[mi][ni] = mfma16(af[mi], bfr[ni], acc[mi][ni]);
        }
    }

#pragma unroll
    for (int mi = 0; mi < 4; ++mi) {
#pragma unroll
        for (int ni = 0; ni < 2; ++ni) {
            int col = nbase + wn + ni * 16 + (lane & 15);
            float bv = bout[col];
#pragma unroll
            for (int q = 0; q < 4; ++q) {
                int rt = mbase + wm + mi * 16 + (lane >> 4) * 4 + q;
                int b = rt & 127, tt = rt >> 7;
                out[((size_t)b * T_ + tt) * OUT_ + col] = acc[mi][ni][q] + bv;
            }
        }
    }
}

// ---------------- launcher ----------------

extern "C" void kernel_launch(void* const* d_in, const int* in_sizes, int n_in,
                              void* d_out, int out_size, void* d_ws, size_t ws_size,
                              hipStream_t stream)
{
    const float* x    = (const float*)d_in[0];
    const float* Wf   = (const float*)d_in[1];
    const float* bf_  = (const float*)d_in[2];
    const float* Wi   = (const float*)d_in[3];
    const float* bi_  = (const float*)d_in[4];
    const float* Wc   = (const float*)d_in[5];
    const float* bc_  = (const float*)d_in[6];
    const float* Wo   = (const float*)d_in[7];
    const float* bo_  = (const float*)d_in[8];
    const float* Wout = (const float*)d_in[9];
    const float* bout = (const float*)d_in[10];
    float* out = (float*)d_out;

    char* ws = (char*)d_ws;
    size_t off = 0;
    auto alloc = [&](size_t bytes) {
        char* p = ws + off;
        off += (bytes + 255) & ~(size_t)255;
        return p;
    };
    ushort* xT   = (ushort*)alloc((size_t)T_ * B_ * IN_ * 2);       // 33.6 MB
    ushort* Wcat = (ushort*)alloc((size_t)NG_ * KC_ * 2);           // 12.6 MB
    float*  bias = (float*) alloc((size_t)NG_ * 4);
    ushort* Wob  = (ushort*)alloc((size_t)OUT_ * H_ * 2);           // 1 MB
    ushort* hs   = (ushort*)alloc((size_t)(T_ + 1) * B_ * H_ * 2);  // 67.4 MB
    float*  cst  = (float*) alloc((size_t)B_ * H_ * 4);             // 0.5 MB

    hipLaunchKernelGGL(prep_w,    dim3(NG_), dim3(256), 0, stream, Wf, Wi, Wc, Wo, Wcat);
    hipLaunchKernelGGL(prep_bias, dim3(16),  dim3(256), 0, stream, bf_, bi_, bc_, bo_, bias);
    hipLaunchKernelGGL(prep_wout, dim3(OUT_),dim3(256), 0, stream, Wout, Wob);
    hipLaunchKernelGGL(prep_x,    dim3(T_ * B_), dim3(256), 0, stream, x, xT);
    hipLaunchKernelGGL(prep_zero, dim3(512), dim3(256), 0, stream, hs, cst);

    for (int t = 0; t < T_; ++t)
        hipLaunchKernelGGL(lstm_step, dim3(64), dim3(256), 0, stream,
                           xT, Wcat, bias, hs, cst, t);

    hipLaunchKernelGGL(out_gemm, dim3(2048), dim3(256), 0, stream,
                       hs + (size_t)B_ * H_, Wob, bout, out);
}

// Round 2
// 4386.209 us; speedup vs baseline: 1.6888x; 1.6888x over previous
//
#include <hip/hip_runtime.h>
#include <stdint.h>

#define B_   128
#define T_   256
#define IN_  512
#define H_   1024
#define NG_  4096   // 4*H (gate-interleaved rows)
#define KC_  1536   // IN+H
#define OUT_ 512
#define NBLK 128
#define NTHR 512

typedef __bf16 bf16x8 __attribute__((ext_vector_type(8)));
typedef float  f32x4  __attribute__((ext_vector_type(4)));

__device__ __forceinline__ ushort f2bf(float f) {
    union { float f; uint32_t u; } v; v.f = f;
    uint32_t u = v.u;
    return (ushort)((u + 0x7FFFu + ((u >> 16) & 1u)) >> 16);  // RNE
}

__device__ __forceinline__ f32x4 mfma16(bf16x8 a, bf16x8 b, f32x4 c) {
    return __builtin_amdgcn_mfma_f32_16x16x32_bf16(a, b, c, 0, 0, 0);
}

// ---------------- prep kernels ----------------

__global__ void prep_w(const float* __restrict__ Wf, const float* __restrict__ Wi,
                       const float* __restrict__ Wc, const float* __restrict__ Wo,
                       ushort* __restrict__ Wcat) {
    int row = blockIdx.x;            // 0..4095 (= 4*j+g)
    int j = row >> 2, g = row & 3;
    const float* W = (g == 0) ? Wf : (g == 1) ? Wi : (g == 2) ? Wc : Wo;
    for (int k = threadIdx.x; k < KC_; k += 256)
        Wcat[(size_t)row * KC_ + k] = f2bf(W[(size_t)j * KC_ + k]);
}

__global__ void prep_bias(const float* __restrict__ bf_, const float* __restrict__ bi_,
                          const float* __restrict__ bc_, const float* __restrict__ bo_,
                          float* __restrict__ bias) {
    int idx = blockIdx.x * 256 + threadIdx.x;  // 16 blocks -> 4096
    int j = idx >> 2, g = idx & 3;
    const float* b = (g == 0) ? bf_ : (g == 1) ? bi_ : (g == 2) ? bc_ : bo_;
    bias[idx] = b[j];
}

__global__ void prep_wout(const float* __restrict__ W, ushort* __restrict__ Wb) {
    int row = blockIdx.x;  // 512
    for (int k = threadIdx.x; k < H_; k += 256)
        Wb[(size_t)row * H_ + k] = f2bf(W[(size_t)row * H_ + k]);
}

__global__ void prep_x(const float* __restrict__ x, ushort* __restrict__ xT) {
    int bid = blockIdx.x;            // t*128 + b
    int t = bid >> 7, b = bid & 127;
    const float* src = x  + ((size_t)b * T_ + t) * IN_;
    ushort*      dst = xT + ((size_t)t * B_ + b) * IN_;
    for (int k = threadIdx.x; k < IN_; k += 256) dst[k] = f2bf(src[k]);
}

__global__ void prep_zero(ushort* __restrict__ hs0, unsigned int* __restrict__ cnt) {
    int idx = blockIdx.x * 256 + threadIdx.x;  // 512*256 = 131072 = B_*H_
    hs0[idx] = 0;
    if (idx < T_ + 1) cnt[idx] = 0u;
}

// ---------------- persistent LSTM kernel ----------------
// 128 blocks x 512 threads (8 waves). Block bx owns 32 gate-columns
// (= 8 hidden units, gate-interleaved). Waves: mh = wave&1 (m-half of 64
// batch rows), kq = wave>>1 (K-quarter of 384). W fragments live in VGPRs
// for the whole kernel; c-state lives in VGPRs; A (x|h) is staged per
// 32-wide K chunk into swizzled LDS; cross-kq reduction via LDS tree.
// Cross-block step barrier: release fetch_add + acquire poll, agent scope.

__launch_bounds__(NTHR, 2)
__global__ void lstm_persist(const ushort* __restrict__ xT,
                             const ushort* __restrict__ Wcat,
                             const float* __restrict__ bias,
                             ushort* __restrict__ hs,
                             unsigned int* cnt)
{
    __shared__ ushort As[4][B_][32];        // 32 KB A staging (4 chunks, one per kq)
    __shared__ float  scratch[4][64][32];   // 32 KB reduction scratch
    __shared__ float  gbuf[B_][32];         // 16 KB gate pre-activations
    __shared__ float  pad_[1024];           // pad to 84 KB -> force 1 block/CU

    const int tid  = threadIdx.x;
    const int lane = tid & 63;
    const int wv   = tid >> 6;        // 0..7
    const int mh   = wv & 1;          // m-half: rows [mh*64, mh*64+64)
    const int kq   = wv >> 1;         // k-quarter: k in [kq*384, kq*384+384)
    const int bx   = blockIdx.x;
    const int nbase = bx * 32;

    pad_[tid & 1023] = 0.f;           // keep pad_ allocated

    // ---- persistent W fragments: breg[nt][r] covers k = kq*384 + r*32 ----
    bf16x8 breg[2][12];
#pragma unroll
    for (int nt = 0; nt < 2; ++nt)
#pragma unroll
        for (int r = 0; r < 12; ++r) {
            const ushort* p = Wcat + (size_t)(nbase + nt * 16 + (lane & 15)) * KC_
                              + kq * 384 + r * 32 + (lane >> 4) * 8;
            breg[nt][r] = *(const bf16x8*)p;
        }

    float biasv[2];
#pragma unroll
    for (int nt = 0; nt < 2; ++nt)
        biasv[nt] = bias[nbase + nt * 16 + (lane & 15)];

    // c-state: items {tid, tid+512} of 1024 (row, unit) pairs
    float creg[2] = {0.f, 0.f};

    const int srow = tid >> 2;        // staging row 0..127
    const int sseg = tid & 3;         // staging 16B segment 0..3

    for (int t = 0; t < T_; ++t) {
        if (t > 0 && tid == 0) {
            while (__hip_atomic_load(cnt + t, __ATOMIC_RELAXED,
                                     __HIP_MEMORY_SCOPE_AGENT) < (unsigned)NBLK)
                __builtin_amdgcn_s_sleep(2);
            (void)__hip_atomic_load(cnt + t, __ATOMIC_ACQUIRE,
                                    __HIP_MEMORY_SCOPE_AGENT);  // L1/L2 invalidate
        }
        __syncthreads();

        f32x4 acc[4][2];
#pragma unroll
        for (int mi = 0; mi < 4; ++mi)
#pragma unroll
            for (int nt = 0; nt < 2; ++nt) acc[mi][nt] = (f32x4){0.f, 0.f, 0.f, 0.f};

        const ushort* xTt = xT + (size_t)t * (B_ * IN_);
        const ushort* ht  = hs + (size_t)t * (B_ * H_);

#pragma unroll
        for (int r = 0; r < 12; ++r) {
            // stage 4 chunks (k = c*384 + r*32, 32 wide) into swizzled LDS
#pragma unroll
            for (int c = 0; c < 4; ++c) {
                const int k0 = c * 384 + r * 32 + sseg * 8;
                const ushort* src = (k0 < IN_)
                    ? (xTt + (size_t)srow * IN_ + k0)
                    : (ht  + (size_t)srow * H_  + (k0 - IN_));
                uint4 v = *(const uint4*)src;
                *(uint4*)&As[c][srow][(sseg ^ (srow & 3)) * 8] = v;
            }
            __syncthreads();
            bf16x8 af[4];
#pragma unroll
            for (int mi = 0; mi < 4; ++mi) {
                const int row = mh * 64 + mi * 16 + (lane & 15);
                af[mi] = *(const bf16x8*)&As[kq][row][(((lane >> 4)) ^ (row & 3)) * 8];
            }
#pragma unroll
            for (int mi = 0; mi < 4; ++mi)
#pragma unroll
                for (int nt = 0; nt < 2; ++nt)
                    acc[mi][nt] = mfma16(af[mi], breg[nt][r], acc[mi][nt]);
            __syncthreads();
        }

        // ---- cross-kq reduction: (kq1->kq0, kq3->kq2), then kq2->kq0 ----
        if (kq == 1 || kq == 3) {
            float* dst = &scratch[mh * 2 + (kq >> 1)][0][0];
#pragma unroll
            for (int mi = 0; mi < 4; ++mi)
#pragma unroll
                for (int nt = 0; nt < 2; ++nt)
#pragma unroll
                    for (int q = 0; q < 4; ++q)
                        dst[(mi * 16 + (lane >> 4) * 4 + q) * 32 + nt * 16 + (lane & 15)]
                            = acc[mi][nt][q];
        }
        __syncthreads();
        if (kq == 0 || kq == 2) {
            const float* s = &scratch[mh * 2 + (kq >> 1)][0][0];
#pragma unroll
            for (int mi = 0; mi < 4; ++mi)
#pragma unroll
                for (int nt = 0; nt < 2; ++nt)
#pragma unroll
                    for (int q = 0; q < 4; ++q)
                        acc[mi][nt][q] += s[(mi * 16 + (lane >> 4) * 4 + q) * 32
                                            + nt * 16 + (lane & 15)];
        }
        __syncthreads();
        if (kq == 2) {
            float* dst = &scratch[mh][0][0];
#pragma unroll
            for (int mi = 0; mi < 4; ++mi)
#pragma unroll
                for (int nt = 0; nt < 2; ++nt)
#pragma unroll
                    for (int q = 0; q < 4; ++q)
                        dst[(mi * 16 + (lane >> 4) * 4 + q) * 32 + nt * 16 + (lane & 15)]
                            = acc[mi][nt][q];
        }
        __syncthreads();
        if (kq == 0) {
            const float* s = &scratch[mh][0][0];
#pragma unroll
            for (int mi = 0; mi < 4; ++mi)
#pragma unroll
                for (int nt = 0; nt < 2; ++nt)
#pragma unroll
                    for (int q = 0; q < 4; ++q) {
                        float v = acc[mi][nt][q]
                                + s[(mi * 16 + (lane >> 4) * 4 + q) * 32
                                    + nt * 16 + (lane & 15)] + biasv[nt];
                        gbuf[mh * 64 + mi * 16 + (lane >> 4) * 4 + q][nt * 16 + (lane & 15)] = v;
                    }
        }
        __syncthreads();

        // ---- cell/hidden update (all 512 threads, c in registers) ----
        ushort* ht1 = hs + (size_t)(t + 1) * (B_ * H_);
#pragma unroll
        for (int i = 0; i < 2; ++i) {
            const int item = i * 512 + tid;
            const int row = item >> 3, u = item & 7;
            f32x4 g = *(const f32x4*)&gbuf[row][u * 4];
            float fg = 1.f / (1.f + __expf(-g[0]));
            float ig = 1.f / (1.f + __expf(-g[1]));
            float ct = tanhf(g[2]);
            float og = 1.f / (1.f + __expf(-g[3]));
            float cn = fg * creg[i] + ig * ct;
            creg[i] = cn;
            ht1[(size_t)row * H_ + bx * 8 + u] = f2bf(og * tanhf(cn));
        }
        __syncthreads();   // drain h stores (vmcnt) before release
        if (tid == 0)
            (void)__hip_atomic_fetch_add(cnt + (t + 1), 1u, __ATOMIC_RELEASE,
                                         __HIP_MEMORY_SCOPE_AGENT);  // wb L2
    }
}

// ---------------- output projection GEMM ----------------

__launch_bounds__(256, 2)
__global__ void out_gemm(const ushort* __restrict__ hsflat,
                         const ushort* __restrict__ Wout,
                         const float* __restrict__ bout,
                         float* __restrict__ out)
{
    __shared__ ushort As2[128 * 64];
    __shared__ ushort Bs2[64 * 64];
    const int tid  = threadIdx.x;
    const int lane = tid & 63;
    const int wave = tid >> 6;
    const int wm = (wave >> 1) * 64;
    const int wn = (wave & 1) * 32;
    const int mbase = (blockIdx.x >> 3) * 128;
    const int nbase = (blockIdx.x & 7) * 64;

    f32x4 acc[4][2];
#pragma unroll
    for (int i = 0; i < 4; i++)
#pragma unroll
        for (int j = 0; j < 2; j++) acc[i][j] = (f32x4){0.f, 0.f, 0.f, 0.f};

    for (int kc = 0; kc < H_ / 64; ++kc) {
        const int k0 = kc * 64;
        __syncthreads();
#pragma unroll
        for (int it = 0; it < 4; ++it) {
            int g = it * 256 + tid;
            int row = g >> 3;
            int seg = g & 7;
            uint4 v = *(const uint4*)(hsflat + (size_t)(mbase + row) * H_ + k0 + seg * 8);
            int dstg = seg ^ (row & 7);
            *(uint4*)&As2[row * 64 + dstg * 8] = v;
        }
#pragma unroll
        for (int it = 0; it < 2; ++it) {
            int g = it * 256 + tid;
            int row = g >> 3;
            int seg = g & 7;
            uint4 v = *(const uint4*)(Wout + (size_t)(nbase + row) * H_ + k0 + seg * 8);
            int dstg = seg ^ (row & 7);
            *(uint4*)&Bs2[row * 64 + dstg * 8] = v;
        }
        __syncthreads();
#pragma unroll
        for (int ks = 0; ks < 2; ++ks) {
            const int kg = ks * 4 + (lane >> 4);
            bf16x8 af[4], bfr[2];
#pragma unroll
            for (int mi = 0; mi < 4; ++mi) {
                int row = wm + mi * 16 + (lane & 15);
                int gi = kg ^ (row & 7);
                af[mi] = *(const bf16x8*)&As2[row * 64 + gi * 8];
            }
#pragma unroll
            for (int ni = 0; ni < 2; ++ni) {
                int row = wn + ni * 16 + (lane & 15);
                int gi = kg ^ (row & 7);
                bfr[ni] = *(const bf16x8*)&Bs2[row * 64 + gi * 8];
            }
#pragma unroll
            for (int mi = 0; mi < 4; ++mi)
#pragma unroll
                for (int ni = 0; ni < 2; ++ni)
                    acc[mi][ni] = mfma16(af[mi], bfr[ni], acc[mi][ni]);
        }
    }

#pragma unroll
    for (int mi = 0; mi < 4; ++mi) {
#pragma unroll
        for (int ni = 0; ni < 2; ++ni) {
            int col = nbase + wn + ni * 16 + (lane & 15);
            float bv = bout[col];
#pragma unroll
            for (int q = 0; q < 4; ++q) {
                int rt = mbase + wm + mi * 16 + (lane >> 4) * 4 + q;
                int b = rt & 127, tt = rt >> 7;
                out[((size_t)b * T_ + tt) * OUT_ + col] = acc[mi][ni][q] + bv;
            }
        }
    }
}

// ---------------- launcher ----------------

extern "C" void kernel_launch(void* const* d_in, const int* in_sizes, int n_in,
                              void* d_out, int out_size, void* d_ws, size_t ws_size,
                              hipStream_t stream)
{
    const float* x    = (const float*)d_in[0];
    const float* Wf   = (const float*)d_in[1];
    const float* bf_  = (const float*)d_in[2];
    const float* Wi   = (const float*)d_in[3];
    const float* bi_  = (const float*)d_in[4];
    const float* Wc   = (const float*)d_in[5];
    const float* bc_  = (const float*)d_in[6];
    const float* Wo   = (const float*)d_in[7];
    const float* bo_  = (const float*)d_in[8];
    const float* Wout = (const float*)d_in[9];
    const float* bout = (const float*)d_in[10];
    float* out = (float*)d_out;

    char* ws = (char*)d_ws;
    size_t off = 0;
    auto alloc = [&](size_t bytes) {
        char* p = ws + off;
        off += (bytes + 255) & ~(size_t)255;
        return p;
    };
    ushort* xT   = (ushort*)alloc((size_t)T_ * B_ * IN_ * 2);       // 33.6 MB
    ushort* Wcat = (ushort*)alloc((size_t)NG_ * KC_ * 2);           // 12.6 MB
    float*  bias = (float*) alloc((size_t)NG_ * 4);
    ushort* Wob  = (ushort*)alloc((size_t)OUT_ * H_ * 2);           // 1 MB
    ushort* hs   = (ushort*)alloc((size_t)(T_ + 1) * B_ * H_ * 2);  // 67.4 MB
    unsigned int* cnt = (unsigned int*)alloc((size_t)(T_ + 1) * 4);

    hipLaunchKernelGGL(prep_w,    dim3(NG_), dim3(256), 0, stream, Wf, Wi, Wc, Wo, Wcat);
    hipLaunchKernelGGL(prep_bias, dim3(16),  dim3(256), 0, stream, bf_, bi_, bc_, bo_, bias);
    hipLaunchKernelGGL(prep_wout, dim3(OUT_),dim3(256), 0, stream, Wout, Wob);
    hipLaunchKernelGGL(prep_x,    dim3(T_ * B_), dim3(256), 0, stream, x, xT);
    hipLaunchKernelGGL(prep_zero, dim3(512), dim3(256), 0, stream, hs, cnt);

    hipLaunchKernelGGL(lstm_persist, dim3(NBLK), dim3(NTHR), 0, stream,
                       xT, Wcat, bias, hs, cnt);

    hipLaunchKernelGGL(out_gemm, dim3(2048), dim3(256), 0, stream,
                       hs + (size_t)B_ * H_, Wob, bout, out);
}

// Round 3
// 3059.365 us; speedup vs baseline: 2.4213x; 1.4337x over previous
//
#include <hip/hip_runtime.h>
#include <stdint.h>

#define B_   128
#define T_   256
#define IN_  512
#define H_   1024
#define NG_  4096   // 4*H (gate-interleaved rows)
#define KC_  1536   // IN+H
#define OUT_ 512
#define NBLK 256    // 8 groups x 32 blocks
#define NTHR 512

typedef __bf16 bf16x8 __attribute__((ext_vector_type(8)));
typedef float  f32x4  __attribute__((ext_vector_type(4)));

__device__ __forceinline__ ushort f2bf(float f) {
    union { float f; uint32_t u; } v; v.f = f;
    uint32_t u = v.u;
    return (ushort)((u + 0x7FFFu + ((u >> 16) & 1u)) >> 16);  // RNE
}

__device__ __forceinline__ f32x4 mfma16(bf16x8 a, bf16x8 b, f32x4 c) {
    return __builtin_amdgcn_mfma_f32_16x16x32_bf16(a, b, c, 0, 0, 0);
}

__device__ __forceinline__ float sigf(float x) {
    return 1.f / (1.f + __expf(-x));
}

// ---------------- prep kernels ----------------

__global__ void prep_w(const float* __restrict__ Wf, const float* __restrict__ Wi,
                       const float* __restrict__ Wc, const float* __restrict__ Wo,
                       ushort* __restrict__ Wcat) {
    int row = blockIdx.x;            // 0..4095 (= 4*j+g)
    int j = row >> 2, g = row & 3;
    const float* W = (g == 0) ? Wf : (g == 1) ? Wi : (g == 2) ? Wc : Wo;
    for (int k = threadIdx.x; k < KC_; k += 256)
        Wcat[(size_t)row * KC_ + k] = f2bf(W[(size_t)j * KC_ + k]);
}

__global__ void prep_bias(const float* __restrict__ bf_, const float* __restrict__ bi_,
                          const float* __restrict__ bc_, const float* __restrict__ bo_,
                          float* __restrict__ bias) {
    int idx = blockIdx.x * 256 + threadIdx.x;  // 16 blocks -> 4096
    int j = idx >> 2, g = idx & 3;
    const float* b = (g == 0) ? bf_ : (g == 1) ? bi_ : (g == 2) ? bc_ : bo_;
    bias[idx] = b[j];
}

__global__ void prep_wout(const float* __restrict__ W, ushort* __restrict__ Wb) {
    int row = blockIdx.x;  // 512
    for (int k = threadIdx.x; k < H_; k += 256)
        Wb[(size_t)row * H_ + k] = f2bf(W[(size_t)row * H_ + k]);
}

__global__ void prep_x(const float* __restrict__ x, ushort* __restrict__ xT) {
    int bid = blockIdx.x;            // t*128 + b
    int t = bid >> 7, b = bid & 127;
    const float* src = x  + ((size_t)b * T_ + t) * IN_;
    ushort*      dst = xT + ((size_t)t * B_ + b) * IN_;
    for (int k = threadIdx.x; k < IN_; k += 256) dst[k] = f2bf(src[k]);
}

__global__ void prep_zero(ushort* __restrict__ hs0, unsigned int* __restrict__ flags) {
    int idx = blockIdx.x * 256 + threadIdx.x;  // 512*256 = 131072 = B_*H_
    hs0[idx] = 0;
    if (idx < NBLK) flags[idx] = 0u;
}

// ---------------- persistent LSTM kernel ----------------
// 256 blocks x 512 threads. Group = bx&7 (8 groups), sub = bx>>3 (32 blocks
// per group). Group g owns batch rows [g*16, g*16+16); block sub owns gate
// columns [sub*128, +128) = 32 hidden units. Waves: nh = wv&3 (32-col
// subtile), kh = wv>>2 (K-half of 768). W lives in VGPRs (192/wave) for the
// whole kernel; c-state is 1 VGPR/thread. A = [x_t | h_t] (16x1536, 48 KB)
// staged ONCE per step into ^(row&7)-swizzled LDS; K-loop has no barriers.
// Group-local flag barrier: per-block release store, 32-lane ballot poll.

__launch_bounds__(NTHR, 2)
__global__ void lstm_persist(const ushort* __restrict__ xT,
                             const ushort* __restrict__ Wcat,
                             const float* __restrict__ bias,
                             ushort* __restrict__ hs,
                             unsigned int* flags)
{
    __shared__ ushort As[16 * 1536];        // 48 KB  A tile, swizzled
    __shared__ float  scr[4][16][32];       // 8 KB   K-half reduction
    __shared__ float  gbuf[4][16 * 32];     // 8 KB   gate planes f,i,c,o

    const int tid  = threadIdx.x;
    const int lane = tid & 63;
    const int wv   = tid >> 6;        // 0..7
    const int nh   = wv & 3;          // n-subtile: cols [nh*32, +32)
    const int kh   = wv >> 2;         // K-half: k in [kh*768, +768)
    const int bx   = blockIdx.x;
    const int grp  = bx & 7;          // group (XCD-affine under bx%8 round-robin)
    const int sub  = bx >> 3;         // 0..31 within group
    const int nbase = sub * 128;      // block's gate-col base
    const int rbase = grp * 16;       // group's batch-row base

    // ---- persistent W fragments: breg[nt][r], k = kh*768 + r*32 ----
    bf16x8 breg[2][24];
#pragma unroll
    for (int nt = 0; nt < 2; ++nt)
#pragma unroll
        for (int r = 0; r < 24; ++r) {
            const int col  = nbase + nh * 32 + nt * 16 + (lane & 15);
            const int koff = kh * 768 + r * 32 + (lane >> 4) * 8;
            breg[nt][r] = *(const bf16x8*)(Wcat + (size_t)col * KC_ + koff);
        }

    float biasv[2];
#pragma unroll
    for (int nt = 0; nt < 2; ++nt)
        biasv[nt] = bias[nbase + nh * 32 + nt * 16 + (lane & 15)];

    float creg = 0.f;                 // c for (row = tid>>5, unit = tid&31)

    const int srow = tid >> 5;        // staging row 0..15
    const int scol = tid & 31;        // staging seg-within-pass

    for (int t = 0; t < T_; ++t) {
        // ---- group barrier: wait for all 32 blocks to publish h_t ----
        if (t > 0 && wv == 0) {
            const bool active = lane < 32;
            const unsigned int* fp = flags + (lane & 31) * 8 + grp;
            while (1) {
                unsigned v = active
                    ? __hip_atomic_load(fp, __ATOMIC_RELAXED, __HIP_MEMORY_SCOPE_AGENT)
                    : ~0u;
                if (__ballot(active && v < (unsigned)t) == 0ull) break;
                __builtin_amdgcn_s_sleep(1);
            }
            (void)__hip_atomic_load(flags + grp, __ATOMIC_ACQUIRE,
                                    __HIP_MEMORY_SCOPE_AGENT);  // cache invalidate
        }
        __syncthreads();

        // ---- stage A = [x_t | h_t] rows rbase..rbase+15 into LDS ----
        const ushort* xTt = xT + ((size_t)t * B_ + rbase) * IN_;
        const ushort* ht  = hs + ((size_t)t * B_ + rbase) * H_;
#pragma unroll
        for (int p = 0; p < 6; ++p) {
            const int s = p * 32 + scol;              // 16B segment 0..191
            const ushort* src = (s < 64)
                ? (xTt + (size_t)srow * IN_ + s * 8)
                : (ht  + (size_t)srow * H_  + (s - 64) * 8);
            uint4 v = *(const uint4*)src;
            *(uint4*)&As[srow * 1536 + (s ^ (srow & 7)) * 8] = v;
        }
        __syncthreads();

        // ---- K-loop: 24 chunks of 32, no barriers ----
        f32x4 acc[2];
        acc[0] = (f32x4){0.f, 0.f, 0.f, 0.f};
        acc[1] = (f32x4){0.f, 0.f, 0.f, 0.f};
        const int arow = lane & 15;
#pragma unroll
        for (int r = 0; r < 24; ++r) {
            const int kseg = kh * 96 + r * 4 + (lane >> 4);
            bf16x8 a = *(const bf16x8*)&As[arow * 1536 + (kseg ^ (arow & 7)) * 8];
            acc[0] = mfma16(a, breg[0][r], acc[0]);
            acc[1] = mfma16(a, breg[1][r], acc[1]);
        }

        // ---- K-half reduction (kh=1 -> scr, kh=0 adds) ----
        if (kh == 1) {
#pragma unroll
            for (int nt = 0; nt < 2; ++nt)
#pragma unroll
                for (int q = 0; q < 4; ++q)
                    scr[nh][(lane >> 4) * 4 + q][nt * 16 + (lane & 15)] = acc[nt][q];
        }
        __syncthreads();
        if (kh == 0) {
#pragma unroll
            for (int nt = 0; nt < 2; ++nt) {
#pragma unroll
                for (int q = 0; q < 4; ++q) {
                    const int row = (lane >> 4) * 4 + q;
                    const int col = nh * 32 + nt * 16 + (lane & 15);  // 0..127
                    float v = acc[nt][q] + scr[nh][row][nt * 16 + (lane & 15)] + biasv[nt];
                    gbuf[col & 3][row * 32 + (col >> 2)] = v;
                }
            }
        }
        __syncthreads();

        // ---- cell/hidden update: thread -> (row = tid>>5, unit = tid&31) ----
        {
            const int row = tid >> 5, u = tid & 31;
            const int gi = row * 32 + u;
            float fg = sigf(gbuf[0][gi]);
            float ig = sigf(gbuf[1][gi]);
            float ct = tanhf(gbuf[2][gi]);
            float og = sigf(gbuf[3][gi]);
            float cn = fg * creg + ig * ct;
            creg = cn;
            hs[((size_t)(t + 1) * B_ + rbase + row) * H_ + sub * 32 + u]
                = f2bf(og * tanhf(cn));
        }
        __syncthreads();   // drain all waves' h stores (vmcnt0 before barrier)
        if (tid == 0)
            __hip_atomic_store(flags + bx, (unsigned)(t + 1), __ATOMIC_RELEASE,
                               __HIP_MEMORY_SCOPE_AGENT);
    }
}

// ---------------- output projection GEMM ----------------

__launch_bounds__(256, 2)
__global__ void out_gemm(const ushort* __restrict__ hsflat,
                         const ushort* __restrict__ Wout,
                         const float* __restrict__ bout,
                         float* __restrict__ out)
{
    __shared__ ushort As2[128 * 64];
    __shared__ ushort Bs2[64 * 64];
    const int tid  = threadIdx.x;
    const int lane = tid & 63;
    const int wave = tid >> 6;
    const int wm = (wave >> 1) * 64;
    const int wn = (wave & 1) * 32;
    const int mbase = (blockIdx.x >> 3) * 128;
    const int nbase = (blockIdx.x & 7) * 64;

    f32x4 acc[4][2];
#pragma unroll
    for (int i = 0; i < 4; i++)
#pragma unroll
        for (int j = 0; j < 2; j++) acc[i][j] = (f32x4){0.f, 0.f, 0.f, 0.f};

    for (int kc = 0; kc < H_ / 64; ++kc) {
        const int k0 = kc * 64;
        __syncthreads();
#pragma unroll
        for (int it = 0; it < 4; ++it) {
            int g = it * 256 + tid;
            int row = g >> 3;
            int seg = g & 7;
            uint4 v = *(const uint4*)(hsflat + (size_t)(mbase + row) * H_ + k0 + seg * 8);
            int dstg = seg ^ (row & 7);
            *(uint4*)&As2[row * 64 + dstg * 8] = v;
        }
#pragma unroll
        for (int it = 0; it < 2; ++it) {
            int g = it * 256 + tid;
            int row = g >> 3;
            int seg = g & 7;
            uint4 v = *(const uint4*)(Wout + (size_t)(nbase + row) * H_ + k0 + seg * 8);
            int dstg = seg ^ (row & 7);
            *(uint4*)&Bs2[row * 64 + dstg * 8] = v;
        }
        __syncthreads();
#pragma unroll
        for (int ks = 0; ks < 2; ++ks) {
            const int kg = ks * 4 + (lane >> 4);
            bf16x8 af[4], bfr[2];
#pragma unroll
            for (int mi = 0; mi < 4; ++mi) {
                int row = wm + mi * 16 + (lane & 15);
                int gi = kg ^ (row & 7);
                af[mi] = *(const bf16x8*)&As2[row * 64 + gi * 8];
            }
#pragma unroll
            for (int ni = 0; ni < 2; ++ni) {
                int row = wn + ni * 16 + (lane & 15);
                int gi = kg ^ (row & 7);
                bfr[ni] = *(const bf16x8*)&Bs2[row * 64 + gi * 8];
            }
#pragma unroll
            for (int mi = 0; mi < 4; ++mi)
#pragma unroll
                for (int ni = 0; ni < 2; ++ni)
                    acc[mi][ni] = mfma16(af[mi], bfr[ni], acc[mi][ni]);
        }
    }

#pragma unroll
    for (int mi = 0; mi < 4; ++mi) {
#pragma unroll
        for (int ni = 0; ni < 2; ++ni) {
            int col = nbase + wn + ni * 16 + (lane & 15);
            float bv = bout[col];
#pragma unroll
            for (int q = 0; q < 4; ++q) {
                int rt = mbase + wm + mi * 16 + (lane >> 4) * 4 + q;
                int b = rt & 127, tt = rt >> 7;
                out[((size_t)b * T_ + tt) * OUT_ + col] = acc[mi][ni][q] + bv;
            }
        }
    }
}

// ---------------- launcher ----------------

extern "C" void kernel_launch(void* const* d_in, const int* in_sizes, int n_in,
                              void* d_out, int out_size, void* d_ws, size_t ws_size,
                              hipStream_t stream)
{
    const float* x    = (const float*)d_in[0];
    const float* Wf   = (const float*)d_in[1];
    const float* bf_  = (const float*)d_in[2];
    const float* Wi   = (const float*)d_in[3];
    const float* bi_  = (const float*)d_in[4];
    const float* Wc   = (const float*)d_in[5];
    const float* bc_  = (const float*)d_in[6];
    const float* Wo   = (const float*)d_in[7];
    const float* bo_  = (const float*)d_in[8];
    const float* Wout = (const float*)d_in[9];
    const float* bout = (const float*)d_in[10];
    float* out = (float*)d_out;

    char* ws = (char*)d_ws;
    size_t off = 0;
    auto alloc = [&](size_t bytes) {
        char* p = ws + off;
        off += (bytes + 255) & ~(size_t)255;
        return p;
    };
    ushort* xT   = (ushort*)alloc((size_t)T_ * B_ * IN_ * 2);       // 33.6 MB
    ushort* Wcat = (ushort*)alloc((size_t)NG_ * KC_ * 2);           // 12.6 MB
    float*  bias = (float*) alloc((size_t)NG_ * 4);
    ushort* Wob  = (ushort*)alloc((size_t)OUT_ * H_ * 2);           // 1 MB
    ushort* hs   = (ushort*)alloc((size_t)(T_ + 1) * B_ * H_ * 2);  // 67.4 MB
    unsigned int* flags = (unsigned int*)alloc((size_t)NBLK * 4);

    hipLaunchKernelGGL(prep_w,    dim3(NG_), dim3(256), 0, stream, Wf, Wi, Wc, Wo, Wcat);
    hipLaunchKernelGGL(prep_bias, dim3(16),  dim3(256), 0, stream, bf_, bi_, bc_, bo_, bias);
    hipLaunchKernelGGL(prep_wout, dim3(OUT_),dim3(256), 0, stream, Wout, Wob);
    hipLaunchKernelGGL(prep_x,    dim3(T_ * B_), dim3(256), 0, stream, x, xT);
    hipLaunchKernelGGL(prep_zero, dim3(512), dim3(256), 0, stream, hs, flags);

    hipLaunchKernelGGL(lstm_persist, dim3(NBLK), dim3(NTHR), 0, stream,
                       xT, Wcat, bias, hs, flags);

    hipLaunchKernelGGL(out_gemm, dim3(2048), dim3(256), 0, stream,
                       hs + (size_t)B_ * H_, Wob, bout, out);
}

// Round 4
// 2900.091 us; speedup vs baseline: 2.5542x; 1.0549x over previous
//
#include <hip/hip_runtime.h>
#include <stdint.h>

#define B_   128
#define T_   256
#define IN_  512
#define H_   1024
#define NG_  4096   // 4*H (gate-interleaved rows)
#define KC_  1536   // IN+H
#define OUT_ 512
#define NBLK 256    // 8 groups x 32 blocks
#define NTHR 512

typedef __bf16 bf16x8 __attribute__((ext_vector_type(8)));
typedef float  f32x4  __attribute__((ext_vector_type(4)));

__device__ __forceinline__ ushort f2bf(float f) {
    union { float f; uint32_t u; } v; v.f = f;
    uint32_t u = v.u;
    return (ushort)((u + 0x7FFFu + ((u >> 16) & 1u)) >> 16);  // RNE
}

__device__ __forceinline__ f32x4 mfma16(bf16x8 a, bf16x8 b, f32x4 c) {
    return __builtin_amdgcn_mfma_f32_16x16x32_bf16(a, b, c, 0, 0, 0);
}

__device__ __forceinline__ float sigf(float x) {
    return 1.f / (1.f + __expf(-x));
}

// ---------------- prep kernels ----------------

__global__ void prep_w(const float* __restrict__ Wf, const float* __restrict__ Wi,
                       const float* __restrict__ Wc, const float* __restrict__ Wo,
                       ushort* __restrict__ Wcat) {
    int row = blockIdx.x;            // 0..4095 (= 4*j+g)
    int j = row >> 2, g = row & 3;
    const float* W = (g == 0) ? Wf : (g == 1) ? Wi : (g == 2) ? Wc : Wo;
    for (int k = threadIdx.x; k < KC_; k += 256)
        Wcat[(size_t)row * KC_ + k] = f2bf(W[(size_t)j * KC_ + k]);
}

__global__ void prep_bias(const float* __restrict__ bf_, const float* __restrict__ bi_,
                          const float* __restrict__ bc_, const float* __restrict__ bo_,
                          float* __restrict__ bias) {
    int idx = blockIdx.x * 256 + threadIdx.x;  // 16 blocks -> 4096
    int j = idx >> 2, g = idx & 3;
    const float* b = (g == 0) ? bf_ : (g == 1) ? bi_ : (g == 2) ? bc_ : bo_;
    bias[idx] = b[j];
}

__global__ void prep_wout(const float* __restrict__ W, ushort* __restrict__ Wb) {
    int row = blockIdx.x;  // 512
    for (int k = threadIdx.x; k < H_; k += 256)
        Wb[(size_t)row * H_ + k] = f2bf(W[(size_t)row * H_ + k]);
}

__global__ void prep_x(const float* __restrict__ x, ushort* __restrict__ xT) {
    int bid = blockIdx.x;            // t*128 + b
    int t = bid >> 7, b = bid & 127;
    const float* src = x  + ((size_t)b * T_ + t) * IN_;
    ushort*      dst = xT + ((size_t)t * B_ + b) * IN_;
    for (int k = threadIdx.x; k < IN_; k += 256) dst[k] = f2bf(src[k]);
}

__global__ void prep_zero(ushort* __restrict__ hs0, unsigned int* __restrict__ flags) {
    int idx = blockIdx.x * 256 + threadIdx.x;  // 512*256 = 131072 = B_*H_
    hs0[idx] = 0;
    if (idx < NBLK) flags[idx] = 0u;
}

// ---------------- persistent LSTM kernel ----------------
// 256 blocks x 512 threads. Group = bx&7 (8 groups, XCD-affine), sub = bx>>3
// (32 blocks/group). Group g owns batch rows [g*16,+16); block sub owns gate
// cols [sub*128,+128) = 32 hidden units. Waves: nh = wv&3 (32-col subtile),
// kh = wv>>2 (K-half of 768). W fragments resident in VGPRs (192/lane —
// requires the (NTHR,1) launch bound; (NTHR,2) made the allocator cap at 128
// and re-stream 384 KB/block/step from L2). c-state is 1 VGPR/thread.
// A = [x_t | h_t] (16x1536, 48 KB) staged once/step, swizzled; x-part loads
// issued BEFORE the barrier poll (x is barrier-independent), h-part after.

__launch_bounds__(NTHR, 1)
__global__ void lstm_persist(const ushort* __restrict__ xT,
                             const ushort* __restrict__ Wcat,
                             const float* __restrict__ bias,
                             ushort* __restrict__ hs,
                             unsigned int* flags)
{
    __shared__ ushort As[16 * 1536];        // 48 KB  A tile, swizzled
    __shared__ float  scr[4][16][33];       // padded: bank-conflict-free
    __shared__ float  gbuf[4][16][33];      // gate planes f,i,c,o (padded)

    const int tid  = threadIdx.x;
    const int lane = tid & 63;
    const int wv   = tid >> 6;        // 0..7
    const int nh   = wv & 3;          // n-subtile: cols [nh*32, +32)
    const int kh   = wv >> 2;         // K-half: k in [kh*768, +768)
    const int bx   = blockIdx.x;
    const int grp  = bx & 7;          // group (XCD-affine under bx%8 round-robin)
    const int sub  = bx >> 3;         // 0..31 within group
    const int nbase = sub * 128;      // block's gate-col base
    const int rbase = grp * 16;       // group's batch-row base

    // ---- persistent W fragments: breg[nt][r], k = kh*768 + r*32 ----
    bf16x8 breg[2][24];
#pragma unroll
    for (int nt = 0; nt < 2; ++nt)
#pragma unroll
        for (int r = 0; r < 24; ++r) {
            const int col  = nbase + nh * 32 + nt * 16 + (lane & 15);
            const int koff = kh * 768 + r * 32 + (lane >> 4) * 8;
            breg[nt][r] = *(const bf16x8*)(Wcat + (size_t)col * KC_ + koff);
        }

    float biasv[2];
#pragma unroll
    for (int nt = 0; nt < 2; ++nt)
        biasv[nt] = bias[nbase + nh * 32 + nt * 16 + (lane & 15)];

    float creg = 0.f;                 // c for (row = tid>>5, unit = tid&31)

    const int srow = tid >> 5;        // staging row 0..15
    const int scol = tid & 31;        // staging seg-within-pass

    for (int t = 0; t < T_; ++t) {
        // ---- issue x-part staging loads early (barrier-independent) ----
        const ushort* xTt = xT + ((size_t)t * B_ + rbase) * IN_;
        uint4 vx0 = *(const uint4*)(xTt + (size_t)srow * IN_ + scol * 8);
        uint4 vx1 = *(const uint4*)(xTt + (size_t)srow * IN_ + (32 + scol) * 8);

        // ---- group barrier: wait for all 32 blocks to publish h_t ----
        if (t > 0 && wv == 0) {
            const bool active = lane < 32;
            const unsigned int* fp = flags + (lane & 31) * 8 + grp;
            while (1) {
                unsigned v = active
                    ? __hip_atomic_load(fp, __ATOMIC_RELAXED, __HIP_MEMORY_SCOPE_AGENT)
                    : ~0u;
                if (__ballot(active && v < (unsigned)t) == 0ull) break;
                __builtin_amdgcn_s_sleep(1);
            }
            (void)__hip_atomic_load(flags + grp, __ATOMIC_ACQUIRE,
                                    __HIP_MEMORY_SCOPE_AGENT);  // cache invalidate
        }
        __syncthreads();

        // ---- stage A = [x_t | h_t] rows rbase..rbase+15 into LDS ----
        const ushort* ht = hs + ((size_t)t * B_ + rbase) * H_;
        uint4 vh[4];
#pragma unroll
        for (int p = 0; p < 4; ++p)
            vh[p] = *(const uint4*)(ht + (size_t)srow * H_ + (p * 32 + scol) * 8);
        *(uint4*)&As[srow * 1536 + ((scol)      ^ (srow & 7)) * 8] = vx0;
        *(uint4*)&As[srow * 1536 + ((32 + scol) ^ (srow & 7)) * 8] = vx1;
#pragma unroll
        for (int p = 0; p < 4; ++p) {
            const int s = 64 + p * 32 + scol;
            *(uint4*)&As[srow * 1536 + (s ^ (srow & 7)) * 8] = vh[p];
        }
        __syncthreads();

        // ---- K-loop: 24 chunks of 32, no barriers ----
        f32x4 acc[2];
        acc[0] = (f32x4){0.f, 0.f, 0.f, 0.f};
        acc[1] = (f32x4){0.f, 0.f, 0.f, 0.f};
        const int arow = lane & 15;
#pragma unroll
        for (int r = 0; r < 24; ++r) {
            const int kseg = kh * 96 + r * 4 + (lane >> 4);
            bf16x8 a = *(const bf16x8*)&As[arow * 1536 + (kseg ^ (arow & 7)) * 8];
            acc[0] = mfma16(a, breg[0][r], acc[0]);
            acc[1] = mfma16(a, breg[1][r], acc[1]);
        }

        // ---- K-half reduction (kh=1 -> scr, kh=0 adds) ----
        if (kh == 1) {
#pragma unroll
            for (int nt = 0; nt < 2; ++nt)
#pragma unroll
                for (int q = 0; q < 4; ++q)
                    scr[nh][(lane >> 4) * 4 + q][nt * 16 + (lane & 15)] = acc[nt][q];
        }
        __syncthreads();
        if (kh == 0) {
#pragma unroll
            for (int nt = 0; nt < 2; ++nt) {
#pragma unroll
                for (int q = 0; q < 4; ++q) {
                    const int row = (lane >> 4) * 4 + q;
                    const int col = nh * 32 + nt * 16 + (lane & 15);  // 0..127
                    float v = acc[nt][q] + scr[nh][row][nt * 16 + (lane & 15)] + biasv[nt];
                    gbuf[col & 3][row][col >> 2] = v;
                }
            }
        }
        __syncthreads();

        // ---- cell/hidden update: thread -> (row = tid>>5, unit = tid&31) ----
        {
            const int row = tid >> 5, u = tid & 31;
            float fg = sigf(gbuf[0][row][u]);
            float ig = sigf(gbuf[1][row][u]);
            float ct = tanhf(gbuf[2][row][u]);
            float og = sigf(gbuf[3][row][u]);
            float cn = fg * creg + ig * ct;
            creg = cn;
            hs[((size_t)(t + 1) * B_ + rbase + row) * H_ + sub * 32 + u]
                = f2bf(og * tanhf(cn));
        }
        __syncthreads();   // drain all waves' h stores (vmcnt0 before barrier)
        if (tid == 0)
            __hip_atomic_store(flags + bx, (unsigned)(t + 1), __ATOMIC_RELEASE,
                               __HIP_MEMORY_SCOPE_AGENT);
    }
}

// ---------------- output projection GEMM ----------------

__launch_bounds__(256, 2)
__global__ void out_gemm(const ushort* __restrict__ hsflat,
                         const ushort* __restrict__ Wout,
                         const float* __restrict__ bout,
                         float* __restrict__ out)
{
    __shared__ ushort As2[128 * 64];
    __shared__ ushort Bs2[64 * 64];
    const int tid  = threadIdx.x;
    const int lane = tid & 63;
    const int wave = tid >> 6;
    const int wm = (wave >> 1) * 64;
    const int wn = (wave & 1) * 32;
    const int mbase = (blockIdx.x >> 3) * 128;
    const int nbase = (blockIdx.x & 7) * 64;

    f32x4 acc[4][2];
#pragma unroll
    for (int i = 0; i < 4; i++)
#pragma unroll
        for (int j = 0; j < 2; j++) acc[i][j] = (f32x4){0.f, 0.f, 0.f, 0.f};

    for (int kc = 0; kc < H_ / 64; ++kc) {
        const int k0 = kc * 64;
        __syncthreads();
#pragma unroll
        for (int it = 0; it < 4; ++it) {
            int g = it * 256 + tid;
            int row = g >> 3;
            int seg = g & 7;
            uint4 v = *(const uint4*)(hsflat + (size_t)(mbase + row) * H_ + k0 + seg * 8);
            int dstg = seg ^ (row & 7);
            *(uint4*)&As2[row * 64 + dstg * 8] = v;
        }
#pragma unroll
        for (int it = 0; it < 2; ++it) {
            int g = it * 256 + tid;
            int row = g >> 3;
            int seg = g & 7;
            uint4 v = *(const uint4*)(Wout + (size_t)(nbase + row) * H_ + k0 + seg * 8);
            int dstg = seg ^ (row & 7);
            *(uint4*)&Bs2[row * 64 + dstg * 8] = v;
        }
        __syncthreads();
#pragma unroll
        for (int ks = 0; ks < 2; ++ks) {
            const int kg = ks * 4 + (lane >> 4);
            bf16x8 af[4], bfr[2];
#pragma unroll
            for (int mi = 0; mi < 4; ++mi) {
                int row = wm + mi * 16 + (lane & 15);
                int gi = kg ^ (row & 7);
                af[mi] = *(const bf16x8*)&As2[row * 64 + gi * 8];
            }
#pragma unroll
            for (int ni = 0; ni < 2; ++ni) {
                int row = wn + ni * 16 + (lane & 15);
                int gi = kg ^ (row & 7);
                bfr[ni] = *(const bf16x8*)&Bs2[row * 64 + gi * 8];
            }
#pragma unroll
            for (int mi = 0; mi < 4; ++mi)
#pragma unroll
                for (int ni = 0; ni < 2; ++ni)
                    acc[mi][ni] = mfma16(af[mi], bfr[ni], acc[mi][ni]);
        }
    }

#pragma unroll
    for (int mi = 0; mi < 4; ++mi) {
#pragma unroll
        for (int ni = 0; ni < 2; ++ni) {
            int col = nbase + wn + ni * 16 + (lane & 15);
            float bv = bout[col];
#pragma unroll
            for (int q = 0; q < 4; ++q) {
                int rt = mbase + wm + mi * 16 + (lane >> 4) * 4 + q;
                int b = rt & 127, tt = rt >> 7;
                out[((size_t)b * T_ + tt) * OUT_ + col] = acc[mi][ni][q] + bv;
            }
        }
    }
}

// ---------------- launcher ----------------

extern "C" void kernel_launch(void* const* d_in, const int* in_sizes, int n_in,
                              void* d_out, int out_size, void* d_ws, size_t ws_size,
                              hipStream_t stream)
{
    const float* x    = (const float*)d_in[0];
    const float* Wf   = (const float*)d_in[1];
    const float* bf_  = (const float*)d_in[2];
    const float* Wi   = (const float*)d_in[3];
    const float* bi_  = (const float*)d_in[4];
    const float* Wc   = (const float*)d_in[5];
    const float* bc_  = (const float*)d_in[6];
    const float* Wo   = (const float*)d_in[7];
    const float* bo_  = (const float*)d_in[8];
    const float* Wout = (const float*)d_in[9];
    const float* bout = (const float*)d_in[10];
    float* out = (float*)d_out;

    char* ws = (char*)d_ws;
    size_t off = 0;
    auto alloc = [&](size_t bytes) {
        char* p = ws + off;
        off += (bytes + 255) & ~(size_t)255;
        return p;
    };
    ushort* xT   = (ushort*)alloc((size_t)T_ * B_ * IN_ * 2);       // 33.6 MB
    ushort* Wcat = (ushort*)alloc((size_t)NG_ * KC_ * 2);           // 12.6 MB
    float*  bias = (float*) alloc((size_t)NG_ * 4);
    ushort* Wob  = (ushort*)alloc((size_t)OUT_ * H_ * 2);           // 1 MB
    ushort* hs   = (ushort*)alloc((size_t)(T_ + 1) * B_ * H_ * 2);  // 67.4 MB
    unsigned int* flags = (unsigned int*)alloc((size_t)NBLK * 4);

    hipLaunchKernelGGL(prep_w,    dim3(NG_), dim3(256), 0, stream, Wf, Wi, Wc, Wo, Wcat);
    hipLaunchKernelGGL(prep_bias, dim3(16),  dim3(256), 0, stream, bf_, bi_, bc_, bo_, bias);
    hipLaunchKernelGGL(prep_wout, dim3(OUT_),dim3(256), 0, stream, Wout, Wob);
    hipLaunchKernelGGL(prep_x,    dim3(T_ * B_), dim3(256), 0, stream, x, xT);
    hipLaunchKernelGGL(prep_zero, dim3(512), dim3(256), 0, stream, hs, flags);

    hipLaunchKernelGGL(lstm_persist, dim3(NBLK), dim3(NTHR), 0, stream,
                       xT, Wcat, bias, hs, flags);

    hipLaunchKernelGGL(out_gemm, dim3(2048), dim3(256), 0, stream,
                       hs + (size_t)B_ * H_, Wob, bout, out);
}